// Round 4
// baseline (4282.770 us; speedup 1.0000x reference)
//
#include <hip/hip_runtime.h>
#include <hip/hip_bf16.h>
#include <cstdint>
#include <cstddef>

#define T_TOK 4096
#define DMODEL 2048
#define DFF 8192
#define NEXP 8
#define NPAIR (T_TOK * 2)

typedef __bf16 bf16_t;
typedef __bf16 bf16x8 __attribute__((ext_vector_type(8)));
typedef float fx4 __attribute__((ext_vector_type(4)));

__device__ __forceinline__ void gload16(const bf16_t* src, bf16_t* dst) {
    __builtin_amdgcn_global_load_lds(
        (const __attribute__((address_space(1))) uint32_t*)(src),
        (__attribute__((address_space(3))) uint32_t*)(dst), 16, 0, 0);
}

__device__ __forceinline__ bf16x8 pack8(const fx4 lo, const fx4 hi) {
    bf16x8 o;
    o[0] = (bf16_t)lo[0]; o[1] = (bf16_t)lo[1]; o[2] = (bf16_t)lo[2]; o[3] = (bf16_t)lo[3];
    o[4] = (bf16_t)hi[0]; o[5] = (bf16_t)hi[1]; o[6] = (bf16_t)hi[2]; o[7] = (bf16_t)hi[3];
    return o;
}

// ---------------- router ----------------
__global__ void router_kernel(const float* __restrict__ gating, int* __restrict__ counts,
                              int* __restrict__ tok_list, float* __restrict__ w_list) {
    int t = blockIdx.x * blockDim.x + threadIdx.x;
    if (t >= T_TOK) return;
    float l[NEXP];
    float mx = -1e30f;
#pragma unroll
    for (int e = 0; e < NEXP; e++) { l[e] = gating[t * NEXP + e]; mx = fmaxf(mx, l[e]); }
#pragma unroll
    for (int e = 0; e < NEXP; e++) { l[e] = __expf(l[e] - mx); }
    int e0 = 0; float p0 = l[0];
#pragma unroll
    for (int e = 1; e < NEXP; e++) { if (l[e] > p0) { p0 = l[e]; e0 = e; } }
    int e1 = -1; float p1 = -1.0f;
#pragma unroll
    for (int e = 0; e < NEXP; e++) { if (e != e0 && l[e] > p1) { p1 = l[e]; e1 = e; } }
    float inv = 1.0f / (p0 + p1);
    int s0 = atomicAdd(&counts[e0], 1);
    tok_list[e0 * T_TOK + s0] = t; w_list[e0 * T_TOK + s0] = p0 * inv;
    int s1 = atomicAdd(&counts[e1], 1);
    tok_list[e1 * T_TOK + s1] = t; w_list[e1 * T_TOK + s1] = p1 * inv;
}

__global__ void scan_kernel(const int* __restrict__ counts, int* __restrict__ offsets) {
    if (threadIdx.x == 0 && blockIdx.x == 0) {
        int acc = 0;
        for (int e = 0; e < NEXP; e++) { offsets[e] = acc; acc += counts[e]; }
        offsets[NEXP] = acc;
    }
}

// ---------------- x fp32 -> bf16 ----------------
__global__ void cvt_x_kernel(const float* __restrict__ x, bf16_t* __restrict__ xb) {
    int i = blockIdx.x * blockDim.x + threadIdx.x;
    const fx4* src = (const fx4*)x;
    fx4 v0 = src[2 * i], v1 = src[2 * i + 1];
    *(bf16x8*)(xb + (size_t)i * 8) = pack8(v0, v1);
}

// ================= gate_up GEMM =================
// 256 thr = 4 waves. tile: M=128 tokens x 64 h-cols (W rows: 64 g + 64 u). BK=64.
// wave: 64M x 32h dual (accg[4][2], accu[4][2]). A: LDS dbuf via global_load_lds.
// W: direct global->reg fragments (fp32 -> bf16 cvt in reg), no LDS, no barrier coupling.
// dispatch: idx = (g3<<8)|(m<<3)|q ; q=XCD, panel y=q+8*(g3&15), e=g3>>4. Panel stays on one XCD.
__global__ __launch_bounds__(256, 4) void gateup_kernel(
    const bf16_t* __restrict__ xb, const float* __restrict__ gup,
    const int* __restrict__ counts, const int* __restrict__ offsets,
    const int* __restrict__ tok_list, bf16_t* __restrict__ h_buf)
{
    const int idx = blockIdx.x;
    const int q = idx & 7;
    const int mslot = (idx >> 3) & 31;
    const int g3 = idx >> 8;            // 0..127
    const int e = g3 >> 4;
    const int cnt = counts[e];
    const int mbase = mslot * 128;
    if (mbase >= cnt) return;
    const int y = q + 8 * (g3 & 15);    // panel 0..127
    const int nb = y * 64;
    const int off_e = offsets[e];

    __shared__ __align__(16) bf16_t lds_a[2][128 * 64];

    const int tid = threadIdx.x;
    const int lane = tid & 63;
    const int w = tid >> 6;
    const int wm = (w >> 1) * 64;
    const int wc = (w & 1);             // h sub-block of 32

    // A staging: 4 gload16 per wave per K-step; 8 rows per instr, pre-swizzled source chunks
    const bf16_t* a_src[4];
    int a_doff[4];
#pragma unroll
    for (int j = 0; j < 4; j++) {
        int row = (w * 4 + j) * 8 + (lane >> 3);
        int cs = (lane & 7) ^ (row & 7);
        int slot = mbase + row;
        int tok = tok_list[e * T_TOK + (slot < cnt ? slot : cnt - 1)];
        a_src[j] = xb + (size_t)tok * DMODEL + cs * 8;
        a_doff[j] = (w * 4 + j) * 512;
    }

    // W fragment base pointers (per-lane row, per-lane k-group)
    const float* gup_e = gup + (size_t)e * (2 * DFF) * DMODEL;
    const int rowg = nb + wc * 32 + (lane & 15);
    const float* pg0 = gup_e + (size_t)rowg * DMODEL + (lane >> 4) * 8;
    const float* pu0 = pg0 + (size_t)DFF * DMODEL;

    fx4 accg[4][2] = {};
    fx4 accu[4][2] = {};

    // prologue: stage A(0)
#pragma unroll
    for (int j = 0; j < 4; j++) gload16(a_src[j], &lds_a[0][a_doff[j]]);
    asm volatile("s_waitcnt vmcnt(0)" ::: "memory");
    __builtin_amdgcn_s_barrier();

    for (int t = 0; t < DMODEL / 64; ++t) {
        const int cur = t & 1;
        if (t + 1 < DMODEL / 64) {
#pragma unroll
            for (int j = 0; j < 4; j++)
                gload16(a_src[j] + (t + 1) * 64, &lds_a[cur ^ 1][a_doff[j]]);
        }
        asm volatile("" ::: "memory");
        const bf16_t* A = lds_a[cur];
        const float* pg_t = pg0 + t * 64;
        const float* pu_t = pu0 + t * 64;
#pragma unroll
        for (int kp = 0; kp < 2; kp++) {
            const float* pg = pg_t + kp * 32;
            const float* pu = pu_t + kp * 32;
            bf16x8 gf[2], uf[2], af[4];
#pragma unroll
            for (int n = 0; n < 2; n++) {
                fx4 l0 = *(const fx4*)(pg + n * 16 * DMODEL);
                fx4 h0 = *(const fx4*)(pg + n * 16 * DMODEL + 4);
                gf[n] = pack8(l0, h0);
                fx4 l1 = *(const fx4*)(pu + n * 16 * DMODEL);
                fx4 h1 = *(const fx4*)(pu + n * 16 * DMODEL + 4);
                uf[n] = pack8(l1, h1);
            }
            const int ke = kp * 4 + (lane >> 4);
#pragma unroll
            for (int m = 0; m < 4; m++) {
                int r = wm + m * 16 + (lane & 15);
                af[m] = *(const bf16x8*)(&A[r * 64 + ((ke ^ (r & 7)) * 8)]);
            }
#pragma unroll
            for (int m = 0; m < 4; m++)
#pragma unroll
                for (int n = 0; n < 2; n++) {
                    accg[m][n] = __builtin_amdgcn_mfma_f32_16x16x32_bf16(af[m], gf[n], accg[m][n], 0, 0, 0);
                    accu[m][n] = __builtin_amdgcn_mfma_f32_16x16x32_bf16(af[m], uf[n], accu[m][n], 0, 0, 0);
                }
        }
        asm volatile("s_waitcnt vmcnt(0)" ::: "memory");
        __builtin_amdgcn_s_barrier();
    }

    // epilogue: h = silu(g) * u -> bf16
    const int colbase = nb + wc * 32 + (lane & 15);
#pragma unroll
    for (int m = 0; m < 4; m++) {
        int rb = wm + m * 16 + ((lane >> 4) * 4);
#pragma unroll
        for (int j = 0; j < 4; j++) {
            int slot = mbase + rb + j;
            if (slot < cnt) {
                size_t hrow = (size_t)(off_e + slot);
#pragma unroll
                for (int n = 0; n < 2; n++) {
                    float g = accg[m][n][j];
                    float u = accu[m][n][j];
                    float hv = g * u / (1.0f + __expf(-g));
                    h_buf[hrow * DFF + colbase + n * 16] = (bf16_t)hv;
                }
            }
        }
    }
}

// ================= down GEMM =================
// 256 thr = 4 waves. tile: M=128 pairs x 128 out-cols. wave: 64x64, acc[4][4]. BK=64, 128 K-steps.
// A (h rows, contiguous) via gload_lds dbuf; W direct global->reg frags.
// dispatch: idx = (e<<9)|(pp<<8)|(m<<3)|q ; panel y=q+8*pp (0..15)
__global__ __launch_bounds__(256, 4) void down_kernel(
    const bf16_t* __restrict__ h_buf, const float* __restrict__ dwn,
    const int* __restrict__ counts, const int* __restrict__ offsets,
    const int* __restrict__ tok_list, const float* __restrict__ w_list,
    float* __restrict__ out)
{
    const int idx = blockIdx.x;
    const int q = idx & 7;
    const int mslot = (idx >> 3) & 31;
    const int rest = idx >> 8;
    const int pp = rest & 1;
    const int e = rest >> 1;
    const int cnt = counts[e];
    const int mbase = mslot * 128;
    if (mbase >= cnt) return;
    const int y = q + 8 * pp;          // 0..15
    const int nbase = y * 128;
    const int off_e = offsets[e];

    __shared__ __align__(16) bf16_t lds_a[2][128 * 64];

    const int tid = threadIdx.x;
    const int lane = tid & 63;
    const int w = tid >> 6;
    const int wm = (w >> 1) * 64;
    const int wn = (w & 1) * 64;

    const bf16_t* a_src[4];
    int a_doff[4];
#pragma unroll
    for (int j = 0; j < 4; j++) {
        int row = (w * 4 + j) * 8 + (lane >> 3);
        int cs = (lane & 7) ^ (row & 7);
        int slot = mbase + row;
        int hrow = off_e + (slot < cnt ? slot : cnt - 1);
        a_src[j] = h_buf + (size_t)hrow * DFF + cs * 8;
        a_doff[j] = (w * 4 + j) * 512;
    }

    const float* dwn_e = dwn + (size_t)e * DMODEL * DFF;
    const int rowd = nbase + wn + (lane & 15);
    const float* pd0 = dwn_e + (size_t)rowd * DFF + (lane >> 4) * 8;

    fx4 acc[4][4] = {};

#pragma unroll
    for (int j = 0; j < 4; j++) gload16(a_src[j], &lds_a[0][a_doff[j]]);
    asm volatile("s_waitcnt vmcnt(0)" ::: "memory");
    __builtin_amdgcn_s_barrier();

    for (int t = 0; t < DFF / 64; ++t) {
        const int cur = t & 1;
        if (t + 1 < DFF / 64) {
#pragma unroll
            for (int j = 0; j < 4; j++)
                gload16(a_src[j] + (t + 1) * 64, &lds_a[cur ^ 1][a_doff[j]]);
        }
        asm volatile("" ::: "memory");
        const bf16_t* A = lds_a[cur];
        const float* pd_t = pd0 + t * 64;
#pragma unroll
        for (int kp = 0; kp < 2; kp++) {
            const float* pd = pd_t + kp * 32;
            bf16x8 bf[4], af[4];
#pragma unroll
            for (int n = 0; n < 4; n++) {
                fx4 l0 = *(const fx4*)(pd + n * 16 * DFF);
                fx4 h0 = *(const fx4*)(pd + n * 16 * DFF + 4);
                bf[n] = pack8(l0, h0);
            }
            const int ke = kp * 4 + (lane >> 4);
#pragma unroll
            for (int m = 0; m < 4; m++) {
                int r = wm + m * 16 + (lane & 15);
                af[m] = *(const bf16x8*)(&A[r * 64 + ((ke ^ (r & 7)) * 8)]);
            }
#pragma unroll
            for (int m = 0; m < 4; m++)
#pragma unroll
                for (int n = 0; n < 4; n++)
                    acc[m][n] = __builtin_amdgcn_mfma_f32_16x16x32_bf16(af[m], bf[n], acc[m][n], 0, 0, 0);
        }
        asm volatile("s_waitcnt vmcnt(0)" ::: "memory");
        __builtin_amdgcn_s_barrier();
    }

    const int colb = nbase + wn + (lane & 15);
#pragma unroll
    for (int m = 0; m < 4; m++) {
        int rb = wm + m * 16 + ((lane >> 4) * 4);
#pragma unroll
        for (int j = 0; j < 4; j++) {
            int slot = mbase + rb + j;
            if (slot < cnt) {
                int tok = tok_list[e * T_TOK + slot];
                float wgt = w_list[e * T_TOK + slot];
#pragma unroll
                for (int n = 0; n < 4; n++)
                    atomicAdd(&out[(size_t)tok * DMODEL + colb + n * 16], wgt * acc[m][n][j]);
            }
        }
    }
}

// ---------------- launch ----------------
extern "C" void kernel_launch(void* const* d_in, const int* in_sizes, int n_in,
                              void* d_out, int out_size, void* d_ws, size_t ws_size,
                              hipStream_t stream) {
    const float* x      = (const float*)d_in[0];
    const float* gating = (const float*)d_in[1];
    const float* gup    = (const float*)d_in[2];
    const float* dwn    = (const float*)d_in[3];
    float* out = (float*)d_out;

    char* ws = (char*)d_ws;
    int*    counts   = (int*)(ws + 0);
    int*    offsets  = (int*)(ws + 64);
    int*    tok_list = (int*)(ws + 128);
    float*  w_list   = (float*)(ws + 128 + 131072);
    bf16_t* xb       = (bf16_t*)(ws + 262400);
    bf16_t* h_buf    = (bf16_t*)(ws + 17039872);

    hipMemsetAsync(counts, 0, 64, stream);
    hipMemsetAsync(out, 0, (size_t)out_size * sizeof(float), stream);

    router_kernel<<<dim3(T_TOK / 256), dim3(256), 0, stream>>>(gating, counts, tok_list, w_list);
    scan_kernel<<<dim3(1), dim3(64), 0, stream>>>(counts, offsets);
    cvt_x_kernel<<<dim3(T_TOK * DMODEL / 8 / 256), dim3(256), 0, stream>>>(x, xb);

    // 128 g3 (e, panel-group) * 32 m-slots * 8 XCD-slots = 32768 blocks
    gateup_kernel<<<dim3(32768), dim3(256), 0, stream>>>(
        xb, gup, counts, offsets, tok_list, h_buf);

    // 8 e * 2 pp * 32 m-slots * 8 XCD-slots = 4096 blocks
    down_kernel<<<dim3(4096), dim3(256), 0, stream>>>(
        h_buf, dwn, counts, offsets, tok_list, w_list, out);
}

// Round 5
// 1441.675 us; speedup vs baseline: 2.9707x; 2.9707x over previous
//
#include <hip/hip_runtime.h>
#include <hip/hip_bf16.h>
#include <cstdint>
#include <cstddef>

#define T_TOK 4096
#define DMODEL 2048
#define DFF 8192
#define NEXP 8
#define NPAIR (T_TOK * 2)

typedef __bf16 bf16_t;
typedef __bf16 bf16x8 __attribute__((ext_vector_type(8)));
typedef float fx4 __attribute__((ext_vector_type(4)));

__device__ __forceinline__ void gload16(const bf16_t* src, bf16_t* dst) {
    __builtin_amdgcn_global_load_lds(
        (const __attribute__((address_space(1))) uint32_t*)(src),
        (__attribute__((address_space(3))) uint32_t*)(dst), 16, 0, 0);
}

__device__ __forceinline__ bf16x8 pack8(const fx4 lo, const fx4 hi) {
    bf16x8 o;
    o[0] = (bf16_t)lo[0]; o[1] = (bf16_t)lo[1]; o[2] = (bf16_t)lo[2]; o[3] = (bf16_t)lo[3];
    o[4] = (bf16_t)hi[0]; o[5] = (bf16_t)hi[1]; o[6] = (bf16_t)hi[2]; o[7] = (bf16_t)hi[3];
    return o;
}

// ---------------- router ----------------
__global__ void router_kernel(const float* __restrict__ gating, int* __restrict__ counts,
                              int* __restrict__ tok_list, float* __restrict__ w_list) {
    int t = blockIdx.x * blockDim.x + threadIdx.x;
    if (t >= T_TOK) return;
    float l[NEXP];
    float mx = -1e30f;
#pragma unroll
    for (int e = 0; e < NEXP; e++) { l[e] = gating[t * NEXP + e]; mx = fmaxf(mx, l[e]); }
#pragma unroll
    for (int e = 0; e < NEXP; e++) { l[e] = __expf(l[e] - mx); }
    int e0 = 0; float p0 = l[0];
#pragma unroll
    for (int e = 1; e < NEXP; e++) { if (l[e] > p0) { p0 = l[e]; e0 = e; } }
    int e1 = -1; float p1 = -1.0f;
#pragma unroll
    for (int e = 0; e < NEXP; e++) { if (e != e0 && l[e] > p1) { p1 = l[e]; e1 = e; } }
    float inv = 1.0f / (p0 + p1);
    int s0 = atomicAdd(&counts[e0], 1);
    tok_list[e0 * T_TOK + s0] = t; w_list[e0 * T_TOK + s0] = p0 * inv;
    int s1 = atomicAdd(&counts[e1], 1);
    tok_list[e1 * T_TOK + s1] = t; w_list[e1 * T_TOK + s1] = p1 * inv;
}

__global__ void scan_kernel(const int* __restrict__ counts, int* __restrict__ offsets) {
    if (threadIdx.x == 0 && blockIdx.x == 0) {
        int acc = 0;
        for (int e = 0; e < NEXP; e++) { offsets[e] = acc; acc += counts[e]; }
        offsets[NEXP] = acc;
    }
}

// ---------------- x fp32 -> bf16 ----------------
__global__ void cvt_x_kernel(const float* __restrict__ x, bf16_t* __restrict__ xb) {
    int i = blockIdx.x * blockDim.x + threadIdx.x;
    const fx4* src = (const fx4*)x;
    fx4 v0 = src[2 * i], v1 = src[2 * i + 1];
    *(bf16x8*)(xb + (size_t)i * 8) = pack8(v0, v1);
}

// ================= gate_up GEMM =================
// R2-v2 internals scaled: 512 thr = 8 waves (4M x 2Nh). tile M=256 tok x 64 h-cols
// (W tile: 64 g rows + 64 u rows), BK=64. wave: 64M x 32h dual acc (accg[4][2], accu[4][2]).
// A: global_load_lds, pre-swizzled source. W: fp32 vec-load -> bf16 -> swizzled ds_write.
// Plain 2-barrier loop, compiler-scheduled waitcnts (no hand asm).
// dispatch: idx=(g2<<7)|(m<<3)|q : q=XCD slot, m=mslot (16), g2=(e<<4)|(ygrp): panel y=q+8*ygrp.
__global__ __launch_bounds__(512, 4) void gateup_kernel(
    const bf16_t* __restrict__ xb, const float* __restrict__ gup,
    const int* __restrict__ counts, const int* __restrict__ offsets,
    const int* __restrict__ tok_list, bf16_t* __restrict__ h_buf)
{
    const int idx = blockIdx.x;
    const int q = idx & 7;
    const int mslot = (idx >> 3) & 15;
    const int g2 = idx >> 7;             // 0..127
    const int e = g2 >> 4;
    const int cnt = counts[e];
    const int mbase = mslot * 256;
    if (mbase >= cnt) return;
    const int y = q + 8 * (g2 & 15);     // panel 0..127
    const int nb = y * 64;
    const int off_e = offsets[e];

    __shared__ __align__(16) bf16_t lds_a[256 * 64];   // 32 KB
    __shared__ __align__(16) bf16_t lds_w[128 * 64];   // 16 KB: rows 0-63 gate, 64-127 up

    const int tid = threadIdx.x;
    const int lane = tid & 63;
    const int w = tid >> 6;
    const int wm = (w >> 1) * 64;
    const int wc = (w & 1);

    // A staging: 32 gload16 per block (4 per wave), 8 rows per instr
    const bf16_t* a_src[4];
    int a_doff[4];
#pragma unroll
    for (int j = 0; j < 4; j++) {
        int row = (w * 4 + j) * 8 + (lane >> 3);
        int cs = (lane & 7) ^ (row & 7);
        int slot = mbase + row;
        int tok = tok_list[e * T_TOK + (slot < cnt ? slot : cnt - 1)];
        a_src[j] = xb + (size_t)tok * DMODEL + cs * 8;
        a_doff[j] = (w * 4 + j) * 512;
    }
    // W staging: 1024 8-float chunks, 2 per thread
    const float* w_src[2];
    int w_st[2];
    const float* gup_e = gup + (size_t)e * (2 * DFF) * DMODEL;
#pragma unroll
    for (int t = 0; t < 2; t++) {
        int cid = t * 512 + tid;
        int row = cid >> 3, c = cid & 7;
        int grow = (row < 64) ? (nb + row) : (DFF + nb + (row - 64));
        w_src[t] = gup_e + (size_t)grow * DMODEL + c * 8;
        w_st[t] = row * 64 + ((c ^ (row & 7)) * 8);
    }

    fx4 accg[4][2] = {};
    fx4 accu[4][2] = {};

    for (int k0 = 0; k0 < DMODEL; k0 += 64) {
#pragma unroll
        for (int j = 0; j < 4; j++) gload16(a_src[j] + k0, &lds_a[a_doff[j]]);
#pragma unroll
        for (int t = 0; t < 2; t++) {
            fx4 lo = *(const fx4*)(w_src[t] + k0);
            fx4 hi = *(const fx4*)(w_src[t] + k0 + 4);
            *(bf16x8*)(&lds_w[w_st[t]]) = pack8(lo, hi);
        }
        __syncthreads();
#pragma unroll
        for (int kp = 0; kp < 2; kp++) {
            const int ke = kp * 4 + (lane >> 4);
            bf16x8 af[4], gf[2], uf[2];
#pragma unroll
            for (int m = 0; m < 4; m++) {
                int r = wm + m * 16 + (lane & 15);
                af[m] = *(const bf16x8*)(&lds_a[r * 64 + ((ke ^ (r & 7)) * 8)]);
            }
#pragma unroll
            for (int n = 0; n < 2; n++) {
                int r = wc * 32 + n * 16 + (lane & 15);
                gf[n] = *(const bf16x8*)(&lds_w[r * 64 + ((ke ^ (r & 7)) * 8)]);
                uf[n] = *(const bf16x8*)(&lds_w[(r + 64) * 64 + ((ke ^ (r & 7)) * 8)]);
            }
#pragma unroll
            for (int m = 0; m < 4; m++)
#pragma unroll
                for (int n = 0; n < 2; n++) {
                    accg[m][n] = __builtin_amdgcn_mfma_f32_16x16x32_bf16(af[m], gf[n], accg[m][n], 0, 0, 0);
                    accu[m][n] = __builtin_amdgcn_mfma_f32_16x16x32_bf16(af[m], uf[n], accu[m][n], 0, 0, 0);
                }
        }
        __syncthreads();
    }

    // epilogue: h = silu(g) * u -> bf16
    const int colbase = nb + wc * 32 + (lane & 15);
#pragma unroll
    for (int m = 0; m < 4; m++) {
        int rb = wm + m * 16 + ((lane >> 4) * 4);
#pragma unroll
        for (int j = 0; j < 4; j++) {
            int slot = mbase + rb + j;
            if (slot < cnt) {
                size_t hrow = (size_t)(off_e + slot);
#pragma unroll
                for (int n = 0; n < 2; n++) {
                    float g = accg[m][n][j];
                    float u = accu[m][n][j];
                    float hv = g * u / (1.0f + __expf(-g));
                    h_buf[hrow * DFF + colbase + n * 16] = (bf16_t)hv;
                }
            }
        }
    }
}

// ================= down GEMM =================
// 512 thr = 8 waves (4M x 2N). tile M=256 pairs x 128 out-cols, BK=64, 128 K-steps.
// wave 64x64: acc[4][4]. A via gload_lds, W fp32->bf16 LDS. 2-barrier loop.
// dispatch: idx=(e<<8)|(pp<<7)|(m<<3)|q : panel y=q+8*pp (16 panels of 128 cols)
__global__ __launch_bounds__(512, 4) void down_kernel(
    const bf16_t* __restrict__ h_buf, const float* __restrict__ dwn,
    const int* __restrict__ counts, const int* __restrict__ offsets,
    const int* __restrict__ tok_list, const float* __restrict__ w_list,
    float* __restrict__ out)
{
    const int idx = blockIdx.x;
    const int q = idx & 7;
    const int mslot = (idx >> 3) & 15;
    const int rest = idx >> 7;
    const int pp = rest & 1;
    const int e = rest >> 1;
    const int cnt = counts[e];
    const int mbase = mslot * 256;
    if (mbase >= cnt) return;
    const int y = q + 8 * pp;          // 0..15
    const int nbase = y * 128;
    const int off_e = offsets[e];

    __shared__ __align__(16) bf16_t lds_a[256 * 64];   // 32 KB
    __shared__ __align__(16) bf16_t lds_w[128 * 64];   // 16 KB

    const int tid = threadIdx.x;
    const int lane = tid & 63;
    const int w = tid >> 6;
    const int wm = (w >> 1) * 64;
    const int wn = (w & 1) * 64;

    const bf16_t* a_src[4];
    int a_doff[4];
#pragma unroll
    for (int j = 0; j < 4; j++) {
        int row = (w * 4 + j) * 8 + (lane >> 3);
        int cs = (lane & 7) ^ (row & 7);
        int slot = mbase + row;
        int hrow = off_e + (slot < cnt ? slot : cnt - 1);
        a_src[j] = h_buf + (size_t)hrow * DFF + cs * 8;
        a_doff[j] = (w * 4 + j) * 512;
    }
    const float* w_src[2];
    int w_st[2];
    const float* dwn_e = dwn + (size_t)e * DMODEL * DFF;
#pragma unroll
    for (int t = 0; t < 2; t++) {
        int cid = t * 512 + tid;
        int row = cid >> 3, c = cid & 7;
        w_src[t] = dwn_e + (size_t)(nbase + row) * DFF + c * 8;
        w_st[t] = row * 64 + ((c ^ (row & 7)) * 8);
    }

    fx4 acc[4][4] = {};

    for (int k0 = 0; k0 < DFF; k0 += 64) {
#pragma unroll
        for (int j = 0; j < 4; j++) gload16(a_src[j] + k0, &lds_a[a_doff[j]]);
#pragma unroll
        for (int t = 0; t < 2; t++) {
            fx4 lo = *(const fx4*)(w_src[t] + k0);
            fx4 hi = *(const fx4*)(w_src[t] + k0 + 4);
            *(bf16x8*)(&lds_w[w_st[t]]) = pack8(lo, hi);
        }
        __syncthreads();
#pragma unroll
        for (int kp = 0; kp < 2; kp++) {
            const int ke = kp * 4 + (lane >> 4);
            bf16x8 af[4], bfr[4];
#pragma unroll
            for (int m = 0; m < 4; m++) {
                int r = wm + m * 16 + (lane & 15);
                af[m] = *(const bf16x8*)(&lds_a[r * 64 + ((ke ^ (r & 7)) * 8)]);
            }
#pragma unroll
            for (int n = 0; n < 4; n++) {
                int r = wn + n * 16 + (lane & 15);
                bfr[n] = *(const bf16x8*)(&lds_w[r * 64 + ((ke ^ (r & 7)) * 8)]);
            }
#pragma unroll
            for (int m = 0; m < 4; m++)
#pragma unroll
                for (int n = 0; n < 4; n++)
                    acc[m][n] = __builtin_amdgcn_mfma_f32_16x16x32_bf16(af[m], bfr[n], acc[m][n], 0, 0, 0);
        }
        __syncthreads();
    }

    const int colb = nbase + wn + (lane & 15);
#pragma unroll
    for (int m = 0; m < 4; m++) {
        int rb = wm + m * 16 + ((lane >> 4) * 4);
#pragma unroll
        for (int j = 0; j < 4; j++) {
            int slot = mbase + rb + j;
            if (slot < cnt) {
                int tok = tok_list[e * T_TOK + slot];
                float wgt = w_list[e * T_TOK + slot];
#pragma unroll
                for (int n = 0; n < 4; n++)
                    atomicAdd(&out[(size_t)tok * DMODEL + colb + n * 16], wgt * acc[m][n][j]);
            }
        }
    }
}

// ---------------- launch ----------------
extern "C" void kernel_launch(void* const* d_in, const int* in_sizes, int n_in,
                              void* d_out, int out_size, void* d_ws, size_t ws_size,
                              hipStream_t stream) {
    const float* x      = (const float*)d_in[0];
    const float* gating = (const float*)d_in[1];
    const float* gup    = (const float*)d_in[2];
    const float* dwn    = (const float*)d_in[3];
    float* out = (float*)d_out;

    char* ws = (char*)d_ws;
    int*    counts   = (int*)(ws + 0);
    int*    offsets  = (int*)(ws + 64);
    int*    tok_list = (int*)(ws + 128);
    float*  w_list   = (float*)(ws + 128 + 131072);
    bf16_t* xb       = (bf16_t*)(ws + 262400);
    bf16_t* h_buf    = (bf16_t*)(ws + 17039872);

    hipMemsetAsync(counts, 0, 64, stream);
    hipMemsetAsync(out, 0, (size_t)out_size * sizeof(float), stream);

    router_kernel<<<dim3(T_TOK / 256), dim3(256), 0, stream>>>(gating, counts, tok_list, w_list);
    scan_kernel<<<dim3(1), dim3(64), 0, stream>>>(counts, offsets);
    cvt_x_kernel<<<dim3(T_TOK * DMODEL / 8 / 256), dim3(256), 0, stream>>>(x, xb);

    // 128 g2 (e,ygrp) * 16 m-slots * 8 XCD-slots = 16384 blocks
    gateup_kernel<<<dim3(16384), dim3(512), 0, stream>>>(
        xb, gup, counts, offsets, tok_list, h_buf);

    // 8 e * 2 pp * 16 m-slots * 8 XCD-slots = 2048 blocks
    down_kernel<<<dim3(2048), dim3(512), 0, stream>>>(
        h_buf, dwn, counts, offsets, tok_list, w_list, out);
}